// Round 18
// baseline (826.659 us; speedup 1.0000x reference)
//
#include <hip/hip_runtime.h>
#include <hip/hip_bf16.h>
#include <stdint.h>

#define SEQ   2048
#define HID   3072
#define NHEADS 24
#define HDIM  128
#define MLPD  12288
#define NCOL1 21504   // 3*HID + MLPD
#define NCOL2 15360   // HID + MLPD
#define MOD3  9216    // 3*HID
#define QKVW  9216    // compact qkv width
#define KSPLIT 8      // lin2 split-K factor

typedef __attribute__((ext_vector_type(4))) float f32x4;
typedef __attribute__((ext_vector_type(8))) short bf16x8;
typedef __attribute__((ext_vector_type(4))) unsigned short u16x4;
typedef __attribute__((ext_vector_type(2))) unsigned short u16x2;

#define VMC(n) asm volatile("s_waitcnt vmcnt(" #n ")" ::: "memory")
#define SB()   __builtin_amdgcn_sched_barrier(0)

__device__ __forceinline__ unsigned short f2bf(float f){
  unsigned u = __float_as_uint(f);
  u = (u + 0x7fffu + ((u >> 16) & 1u)) >> 16;   // RTNE
  return (unsigned short)u;
}
__device__ __forceinline__ float bf2f(unsigned short u){
  return __uint_as_float(((unsigned)u) << 16);
}

__device__ __forceinline__ void gload_lds16(const void* g, void* l){
  __builtin_amdgcn_global_load_lds(
      (const __attribute__((address_space(1))) unsigned int*)g,
      (__attribute__((address_space(3))) unsigned int*)l, 16, 0, 0);
}

__device__ __forceinline__ float gelu_tanh(float x){
  float u = 0.7978845608028654f * (x + 0.044715f * x * x * x);
  float t = 1.f - 2.f / (__expf(2.f * u) + 1.f);   // tanh(u)
  return 0.5f * x * (1.f + t);
}

// ---------------------------------------------------------------- small ops
__global__ void silu_kernel(const float* __restrict__ vec, float* __restrict__ sv){
  int i = blockIdx.x * 256 + threadIdx.x;
  if (i < HID){ float v = vec[i]; sv[i] = v / (1.f + __expf(-v)); }
}

__global__ void mod_gemv(const float* __restrict__ sv, const float* __restrict__ W,
                         const float* __restrict__ b, float* __restrict__ mod){
  int n  = blockIdx.x * 32 + (threadIdx.x & 31);
  int ks = threadIdx.x >> 5;               // 0..7, each 384 k
  float acc = 0.f;
  int k0 = ks * 384;
  #pragma unroll 4
  for (int k = k0; k < k0 + 384; ++k)
    acc += sv[k] * W[(size_t)k * MOD3 + n];
  __shared__ float red[8][32];
  red[ks][threadIdx.x & 31] = acc;
  __syncthreads();
  if (ks == 0){
    float a = 0.f;
    #pragma unroll
    for (int i = 0; i < 8; ++i) a += red[i][threadIdx.x & 31];
    mod[n] = a + b[n];
  }
}

__global__ __launch_bounds__(256)
void ln_mod_kernel(const float* __restrict__ x, const float* __restrict__ mod,
                   unsigned short* __restrict__ xmod){
  int l = blockIdx.x, t = threadIdx.x;
  const float* row = x + (size_t)l * HID;
  f32x4 v[3];
  float s = 0.f, s2 = 0.f;
  #pragma unroll
  for (int i = 0; i < 3; ++i){
    v[i] = *(const f32x4*)(row + (t + i * 256) * 4);
    #pragma unroll
    for (int j = 0; j < 4; ++j){ s += v[i][j]; s2 += v[i][j] * v[i][j]; }
  }
  #pragma unroll
  for (int m = 1; m < 64; m <<= 1){ s += __shfl_xor(s, m, 64); s2 += __shfl_xor(s2, m, 64); }
  __shared__ float red[8];
  int wv = t >> 6, ln = t & 63;
  if (ln == 0){ red[wv] = s; red[4 + wv] = s2; }
  __syncthreads();
  s  = red[0] + red[1] + red[2] + red[3];
  s2 = red[4] + red[5] + red[6] + red[7];
  float mu  = s * (1.f / HID);
  float var = s2 * (1.f / HID) - mu * mu;
  float rs  = rsqrtf(var + 1e-6f);
  #pragma unroll
  for (int i = 0; i < 3; ++i){
    int c = (t + i * 256) * 4;
    f32x4 sh = *(const f32x4*)(mod + c);
    f32x4 sc = *(const f32x4*)(mod + HID + c);
    u16x4 o;
    #pragma unroll
    for (int j = 0; j < 4; ++j){
      float xn = (v[i][j] - mu) * rs;
      o[j] = f2bf((1.f + sc[j]) * xn + sh[j]);
    }
    *(u16x4*)(xmod + (size_t)l * HID + c) = o;
  }
}

// fp32 (R x C) -> bf16 (C x R)
__global__ __launch_bounds__(256)
void transpose_f2b(const float* __restrict__ in, unsigned short* __restrict__ out,
                   int R, int C){
  __shared__ float tile[64][65];
  int rt = blockIdx.y * 64, ct = blockIdx.x * 64;
  int t = threadIdx.x;
  int r0 = t >> 4, c0 = (t & 15) * 4;
  #pragma unroll
  for (int ph = 0; ph < 4; ++ph){
    int r = r0 + ph * 16;
    f32x4 v = *(const f32x4*)(in + (size_t)(rt + r) * C + ct + c0);
    tile[r][c0 + 0] = v[0]; tile[r][c0 + 1] = v[1];
    tile[r][c0 + 2] = v[2]; tile[r][c0 + 3] = v[3];
  }
  __syncthreads();
  #pragma unroll
  for (int ph = 0; ph < 4; ++ph){
    int r = r0 + ph * 16;
    u16x4 o;
    #pragma unroll
    for (int i = 0; i < 4; ++i) o[i] = f2bf(tile[c0 + i][r]);
    *(u16x4*)(out + (size_t)(ct + r) * R + rt + c0) = o;
  }
}

// per-head bf16 (R x C) -> bf16 (C x R)   (V -> V^T)
__global__ __launch_bounds__(256)
void transpose_b2b_head(const unsigned short* __restrict__ in,
                        unsigned short* __restrict__ out, int R, int C){
  __shared__ unsigned short tile[64][68];
  int h = blockIdx.z;
  const unsigned short* inh = in + (size_t)h * R * C;
  unsigned short* outh = out + (size_t)h * R * C;
  int rt = blockIdx.y * 64, ct = blockIdx.x * 64;
  int t = threadIdx.x;
  int r0 = t >> 4, c0 = (t & 15) * 4;
  #pragma unroll
  for (int ph = 0; ph < 4; ++ph){
    int r = r0 + ph * 16;
    u16x4 v = *(const u16x4*)(inh + (size_t)(rt + r) * C + ct + c0);
    tile[r][c0 + 0] = v[0]; tile[r][c0 + 1] = v[1];
    tile[r][c0 + 2] = v[2]; tile[r][c0 + 3] = v[3];
  }
  __syncthreads();
  #pragma unroll
  for (int ph = 0; ph < 4; ++ph){
    int r = r0 + ph * 16;
    u16x4 o;
    #pragma unroll
    for (int i = 0; i < 4; ++i) o[i] = tile[c0 + i][r];
    *(u16x4*)(outh + (size_t)(ct + r) * R + rt + c0) = o;
  }
}

// RMS-norm + RoPE for q,k; passthrough v. One wave per (l, head). hq is bf16 [SEQ][9216].
__global__ void qkv_prep(const unsigned short* __restrict__ hq, const float* __restrict__ pe,
                         const float* __restrict__ qscale, const float* __restrict__ kscale,
                         unsigned short* __restrict__ qb, unsigned short* __restrict__ kb,
                         unsigned short* __restrict__ vb){
  int l = blockIdx.x, hh = blockIdx.y, lane = threadIdx.x;  // 64 threads
  const unsigned short* row = hq + (size_t)l * QKVW;
  int d = lane * 2;
  u16x2 qv = *(const u16x2*)(row + hh * HDIM + d);
  u16x2 kv = *(const u16x2*)(row + HID + hh * HDIM + d);
  u16x2 vv = *(const u16x2*)(row + 2 * HID + hh * HDIM + d);
  float qx = bf2f(qv[0]), qy = bf2f(qv[1]);
  float kx = bf2f(kv[0]), ky = bf2f(kv[1]);
  float sq = qx * qx + qy * qy;
  float sk = kx * kx + ky * ky;
  #pragma unroll
  for (int m = 1; m < 64; m <<= 1){ sq += __shfl_xor(sq, m, 64); sk += __shfl_xor(sk, m, 64); }
  float rq = rsqrtf(sq * (1.f / HDIM) + 1e-6f);
  float rk = rsqrtf(sk * (1.f / HDIM) + 1e-6f);
  float2 qs2 = *(const float2*)(qscale + d);
  float2 ks2 = *(const float2*)(kscale + d);
  float q0 = qx * rq * qs2.x, q1 = qy * rq * qs2.y;
  float k0 = kx * rk * ks2.x, k1 = ky * rk * ks2.y;
  f32x4 p4 = *(const f32x4*)(pe + (size_t)l * 256 + lane * 4);  // [p][a][b]
  const float sscl = 0.08838834764831845f;  // 1/sqrt(128), folded into q
  float qo0 = (p4[0] * q0 + p4[1] * q1) * sscl;
  float qo1 = (p4[2] * q0 + p4[3] * q1) * sscl;
  float ko0 =  p4[0] * k0 + p4[1] * k1;
  float ko1 =  p4[2] * k0 + p4[3] * k1;
  size_t base = ((size_t)hh * SEQ + l) * HDIM + d;
  u16x2 o;
  o[0] = f2bf(qo0); o[1] = f2bf(qo1); *(u16x2*)(qb + base) = o;
  o[0] = f2bf(ko0); o[1] = f2bf(ko1); *(u16x2*)(kb + base) = o;
  o[0] = vv[0];     o[1] = vv[1];     *(u16x2*)(vb + base) = o;
}

// --------------------- 256x256 row-split half-tile GEMM (2 barriers/K-tile, R17 frozen) ---------------------
//   P0  : gate {Au,Bu}(t) VMC(8|4); barrier; read Au(8)+Bu(4); stage Bl(t+1); 16 MFMA
//   P12 : gate {Bl,Al}(t) VMC(6|0); barrier; read Bl(4)+Al(8); stage Al(t+1),Au(t+2); 32 MFMA
//   P3  : (no barrier/gate/reads) stage Bu(t+2); 16 MFMA
template<int EPI>
__global__ __launch_bounds__(512)
void gemm256(const unsigned short* __restrict__ A, const unsigned short* __restrict__ BT,
             const float* __restrict__ bias, unsigned short* __restrict__ out0,
             unsigned short* __restrict__ out1,
             int M, int N, int ldA, int ldB, int kchunk){
  __shared__ unsigned short Ls[65536];   // A: [buf][half][128*64] @0; B same @32768. 128 KB.
  int nxy = gridDim.x * gridDim.y;
  int nwg = nxy * gridDim.z;
  int fid = (blockIdx.z * gridDim.y + blockIdx.y) * gridDim.x + blockIdx.x;
  int nid = (fid & 7) * (nwg >> 3) + (fid >> 3);    // nwg % 8 == 0 by grid choice
  int ksz = nid / nxy, rem = nid % nxy;
  int bm  = rem % gridDim.y, bn = rem / gridDim.y;  // bm-fast within XCD chunk
  int k0 = ksz * kchunk;
  int nk = kchunk >> 6;                  // BK = 64
  int tid = threadIdx.x, wave = tid >> 6, lane = tid & 63, lg = lane >> 4, lr = lane & 15;
  int wr = wave >> 2, wc = wave & 3;     // 2 x 4 wave grid

  // staging: half = 128 rows x 64 cols; granule g in [0,1024): row=g>>3, cg=g&7 (16B)
  int rh = tid >> 3;                     // rows 0..63 (g0); g1 adds 64 (row&7 unchanged)
  int sc = (((tid & 7) ^ (rh & 7)) * 8); // swizzled source col (elements)
  const unsigned short* pA0 = A  + (size_t)(bm * 256 + rh     ) * ldA + k0 + sc;
  const unsigned short* pA1 = A  + (size_t)(bm * 256 + rh + 64) * ldA + k0 + sc;
  const unsigned short* pB0 = BT + (size_t)(bn * 256 + rh     ) * ldB + k0 + sc;
  const unsigned short* pB1 = BT + (size_t)(bn * 256 + rh + 64) * ldB + k0 + sc;
  int d0 = (wave * 64) * 8, d1 = (512 + wave * 64) * 8;

  auto stageA = [&](int t, int half){
    unsigned short* h = Ls + (((t & 1) * 2 + half) << 13);
    size_t ro = (size_t)(half * 128) * ldA + t * 64;
    gload_lds16(pA0 + ro, h + d0);
    gload_lds16(pA1 + ro, h + d1);
  };
  auto stageB = [&](int t, int half){
    unsigned short* h = Ls + 32768 + (((t & 1) * 2 + half) << 13);
    size_t ro = (size_t)(half * 128) * ldB + t * 64;
    gload_lds16(pB0 + ro, h + d0);
    gload_lds16(pB1 + ro, h + d1);
  };

  // ds_read offsets (elements) within a half, swizzle-matched
  int offA[4][2], offB[2][2];
  #pragma unroll
  for (int mm = 0; mm < 4; ++mm){
    int row = wr * 64 + mm * 16 + lr;
    #pragma unroll
    for (int ks = 0; ks < 2; ++ks)
      offA[mm][ks] = row * 64 + (((ks * 4 + lg) ^ (row & 7)) * 8);
  }
  #pragma unroll
  for (int nn = 0; nn < 2; ++nn){
    int row = wc * 32 + nn * 16 + lr;
    #pragma unroll
    for (int ks = 0; ks < 2; ++ks)
      offB[nn][ks] = row * 64 + (((ks * 4 + lg) ^ (row & 7)) * 8);
  }

  const f32x4 fz = 0.0f;
  f32x4 acc[8][4];   // [m: 0-3 upper rows, 4-7 lower][n: 0-1 upper cols, 2-3 lower]
  #pragma unroll
  for (int i = 0; i < 8; ++i)
    #pragma unroll
    for (int j = 0; j < 4; ++j) acc[i][j] = fz;

  // prologue: Au0 Bu0 Bl0 Al0 Au1 Bu1
  stageA(0, 0); stageB(0, 0); stageB(0, 1); stageA(0, 1);
  if (nk > 1){ stageA(1, 0); stageB(1, 0); }

  for (int t = 0; t < nk; ++t){
    const unsigned short* Au_ = Ls + (((t & 1) * 2 + 0) << 13);
    const unsigned short* Al_ = Ls + (((t & 1) * 2 + 1) << 13);
    const unsigned short* Bu_ = Ls + 32768 + (((t & 1) * 2 + 0) << 13);
    const unsigned short* Bl_ = Ls + 32768 + (((t & 1) * 2 + 1) << 13);
    bool more1 = (t + 1 < nk), more2 = (t + 2 < nk);
    bf16x8 am[4][2], am4[4][2], b01[2][2], b23[2][2];
    // ---------------- P0: gate {Au,Bu}(t); read Au/Bu frags; stage Bl(t+1); 16 MFMA
    if (more1) VMC(8); else VMC(4);
    __builtin_amdgcn_s_barrier();
    SB();
    #pragma unroll
    for (int mm = 0; mm < 4; ++mm)
      #pragma unroll
      for (int ks = 0; ks < 2; ++ks) am[mm][ks] = *(const bf16x8*)&Au_[offA[mm][ks]];
    #pragma unroll
    for (int nn = 0; nn < 2; ++nn)
      #pragma unroll
      for (int ks = 0; ks < 2; ++ks) b01[nn][ks] = *(const bf16x8*)&Bu_[offB[nn][ks]];
    if (more1) stageB(t + 1, 1);
    SB();
    __builtin_amdgcn_s_setprio(1);
    #pragma unroll
    for (int mm = 0; mm < 4; ++mm)
      #pragma unroll
      for (int nn = 0; nn < 2; ++nn)
        #pragma unroll
        for (int ks = 0; ks < 2; ++ks)
          acc[mm][nn] = __builtin_amdgcn_mfma_f32_16x16x32_bf16(am[mm][ks], b01[nn][ks], acc[mm][nn], 0, 0, 0);
    __builtin_amdgcn_s_setprio(0);
    SB();
    // ---------------- P12: gate {Bl,Al}(t); read Bl/Al frags; stage Al(t+1),Au(t+2); 32 MFMA
    if (more1) VMC(6); else VMC(0);
    __builtin_amdgcn_s_barrier();
    SB();
    #pragma unroll
    for (int nn = 0; nn < 2; ++nn)
      #pragma unroll
      for (int ks = 0; ks < 2; ++ks) b23[nn][ks] = *(const bf16x8*)&Bl_[offB[nn][ks]];
    #pragma unroll
    for (int mm = 0; mm < 4; ++mm)
      #pragma unroll
      for (int ks = 0; ks < 2; ++ks) am4[mm][ks] = *(const bf16x8*)&Al_[offA[mm][ks]];
    if (more1) stageA(t + 1, 1);
    if (more2) stageA(t + 2, 0);
    SB();
    __builtin_amdgcn_s_setprio(1);
    #pragma unroll
    for (int mm = 0; mm < 4; ++mm)
      #pragma unroll
      for (int nn = 0; nn < 2; ++nn)
        #pragma unroll
        for (int ks = 0; ks < 2; ++ks)
          acc[mm][nn + 2] = __builtin_amdgcn_mfma_f32_16x16x32_bf16(am[mm][ks], b23[nn][ks], acc[mm][nn + 2], 0, 0, 0);
    #pragma unroll
    for (int mm = 0; mm < 4; ++mm)
      #pragma unroll
      for (int nn = 0; nn < 2; ++nn)
        #pragma unroll
        for (int ks = 0; ks < 2; ++ks)
          acc[mm + 4][nn] = __builtin_amdgcn_mfma_f32_16x16x32_bf16(am4[mm][ks], b01[nn][ks], acc[mm + 4][nn], 0, 0, 0);
    __builtin_amdgcn_s_setprio(0);
    SB();
    // ---------------- P3 (no barrier/gate/reads): stage Bu(t+2); 16 MFMA
    if (more2) stageB(t + 2, 0);
    SB();
    __builtin_amdgcn_s_setprio(1);
    #pragma unroll
    for (int mm = 0; mm < 4; ++mm)
      #pragma unroll
      for (int nn = 0; nn < 2; ++nn)
        #pragma unroll
        for (int ks = 0; ks < 2; ++ks)
          acc[mm + 4][nn + 2] = __builtin_amdgcn_mfma_f32_16x16x32_bf16(am4[mm][ks], b23[nn][ks], acc[mm + 4][nn + 2], 0, 0, 0);
    __builtin_amdgcn_s_setprio(0);
    SB();
  }

  // output mapping: row = bm*256 + wr*64 + (m&3)*16 + (m>>2)*128 + lg*4 + jj
  //                 col = bn*256 + wc*32 + (n&1)*16 + (n>>1)*128 + lr
  if constexpr (EPI == 0){
    if (bn < MOD3 / 256){                       // block-uniform: whole tile -> hq
      #pragma unroll
      for (int m = 0; m < 8; ++m)
        #pragma unroll
        for (int n = 0; n < 4; ++n){
          int col = bn * 256 + wc * 32 + (n & 1) * 16 + (n >> 1) * 128 + lr;
          float bv = bias[col];
          #pragma unroll
          for (int jj = 0; jj < 4; ++jj){
            int row = bm * 256 + wr * 64 + (m & 3) * 16 + (m >> 2) * 128 + lg * 4 + jj;
            out0[(size_t)row * QKVW + col] = f2bf(acc[m][n][jj] + bv);
          }
        }
    } else {                                    // whole tile -> gelu -> a2
      #pragma unroll
      for (int m = 0; m < 8; ++m)
        #pragma unroll
        for (int n = 0; n < 4; ++n){
          int col = bn * 256 + wc * 32 + (n & 1) * 16 + (n >> 1) * 128 + lr;
          float bv = bias[col];
          #pragma unroll
          for (int jj = 0; jj < 4; ++jj){
            int row = bm * 256 + wr * 64 + (m & 3) * 16 + (m >> 2) * 128 + lg * 4 + jj;
            out1[(size_t)row * NCOL2 + (col - 2 * HID)] = f2bf(gelu_tanh(acc[m][n][jj] + bv));
          }
        }
    }
  } else {
    unsigned short* P = out0 + (size_t)ksz * M * N;
    #pragma unroll
    for (int m = 0; m < 8; ++m)
      #pragma unroll
      for (int n = 0; n < 4; ++n){
        int col = bn * 256 + wc * 32 + (n & 1) * 16 + (n >> 1) * 128 + lr;
        #pragma unroll
        for (int jj = 0; jj < 4; ++jj){
          int row = bm * 256 + wr * 64 + (m & 3) * 16 + (m >> 2) * 128 + lg * 4 + jj;
          P[(size_t)row * N + col] = f2bf(acc[m][n][jj]);
        }
      }
  }
}

// split-K reduce (bf16 partials) + bias + gate*(.) + residual  (lin2 epilogue)
__global__ __launch_bounds__(256)
void reduce_lin2(const unsigned short* __restrict__ part, const float* __restrict__ x,
                 const float* __restrict__ gate, const float* __restrict__ bias,
                 float* __restrict__ out){
  int i4 = blockIdx.x * 256 + threadIdx.x;          // over 2048*3072/4
  int c4 = i4 % (HID / 4);
  f32x4 s = 0.0f;
  #pragma unroll
  for (int ks = 0; ks < KSPLIT; ++ks){
    u16x4 p = *(const u16x4*)(part + (size_t)ks * SEQ * HID + (size_t)i4 * 4);
    #pragma unroll
    for (int j = 0; j < 4; ++j) s[j] += bf2f(p[j]);
  }
  f32x4 xv = *(const f32x4*)(x + (size_t)i4 * 4);
  f32x4 gv = *(const f32x4*)(gate + c4 * 4);
  f32x4 bv = *(const f32x4*)(bias + c4 * 4);
  f32x4 o;
  #pragma unroll
  for (int j = 0; j < 4; ++j) o[j] = xv[j] + gv[j] * (s[j] + bv[j]);
  *(f32x4*)(out + (size_t)i4 * 4) = o;
}

// -------------------------------------------------------- flash attention (+T13 defer-max)
__global__ __launch_bounds__(256)
void attn_kernel(const unsigned short* __restrict__ qb, const unsigned short* __restrict__ kb,
                 const unsigned short* __restrict__ vt, unsigned short* __restrict__ a2){
  __shared__ unsigned short Ksm[64 * 128];   // [kv][d], XOR-swizzled
  __shared__ unsigned short Vsm[128 * 64];   // [d][kv], XOR-swizzled
  __shared__ unsigned short Psm[4][16 * 64]; // per-wave [q][kv], XOR-swizzled
  int fid = blockIdx.y * gridDim.x + blockIdx.x;   // 768 blocks
  int nid = (fid & 7) * 96 + (fid >> 3);
  int hh = nid / (SEQ / 64), qt = nid % (SEQ / 64);
  int tid = threadIdx.x, wave = tid >> 6, lane = tid & 63, lg = lane >> 4, lr = lane & 15;
  const unsigned short* Kh = kb + (size_t)hh * SEQ * HDIM;
  const unsigned short* Vh = vt + (size_t)hh * HDIM * SEQ;
  const unsigned short* Qh = qb + (size_t)hh * SEQ * HDIM;
  int q0 = qt * 64 + wave * 16;

  bf16x8 aq[4];
  #pragma unroll
  for (int kk = 0; kk < 4; ++kk)
    aq[kk] = *(const bf16x8*)(Qh + (size_t)(q0 + lr) * HDIM + kk * 32 + lg * 8);

  const f32x4 fzero = 0.0f;
  f32x4 acc_o[8];
  #pragma unroll
  for (int n = 0; n < 8; ++n) acc_o[n] = fzero;
  float mrun[4] = {-1e30f, -1e30f, -1e30f, -1e30f};
  float lrun[4] = {0.f, 0.f, 0.f, 0.f};

  for (int t = 0; t < SEQ / 64; ++t){
    __syncthreads();
    const unsigned short* Kt = Kh + (size_t)t * 64 * HDIM;
    const unsigned short* Vt = Vh + t * 64;
    #pragma unroll
    for (int r = 0; r < 4; ++r){
      int G  = r * 256 + tid;
      int Gs = G ^ ((G >> 4) & 7);
      gload_lds16(Kt + Gs * 8, (void*)&Ksm[(r * 256 + wave * 64) * 8]);
      int Gv = G ^ ((G >> 3) & 7);
      gload_lds16(Vt + (size_t)(Gv >> 3) * SEQ + (Gv & 7) * 8,
                  (void*)&Vsm[(r * 256 + wave * 64) * 8]);
    }
    __syncthreads();

    f32x4 sacc[4];
    #pragma unroll
    for (int j = 0; j < 4; ++j) sacc[j] = fzero;
    #pragma unroll
    for (int j = 0; j < 4; ++j){
      int kv = j * 16 + lr;
      #pragma unroll
      for (int kk = 0; kk < 4; ++kk){
        int bo = kv * 256 + (kk * 32 + lg * 8) * 2;
        bo ^= (kv & 7) << 4;
        bf16x8 bk = *(const bf16x8*)((const char*)Ksm + bo);
        sacc[j] = __builtin_amdgcn_mfma_f32_16x16x32_bf16(aq[kk], bk, sacc[j], 0, 0, 0);
      }
    }
    // per-row tile max (16-lane group reduce)
    float pmax[4];
    #pragma unroll
    for (int jj = 0; jj < 4; ++jj){
      float m_ = fmaxf(fmaxf(sacc[0][jj], sacc[1][jj]), fmaxf(sacc[2][jj], sacc[3][jj]));
      #pragma unroll
      for (int mk = 1; mk < 16; mk <<= 1) m_ = fmaxf(m_, __shfl_xor(m_, mk, 64));
      pmax[jj] = m_;
    }
    // T13 defer-max: skip O-rescale when growth bounded (wave-uniform)
    bool defer = __all((pmax[0] - mrun[0] <= 8.f) & (pmax[1] - mrun[1] <= 8.f) &
                       (pmax[2] - mrun[2] <= 8.f) & (pmax[3] - mrun[3] <= 8.f));
    if (!defer){
      float scl[4];
      #pragma unroll
      for (int jj = 0; jj < 4; ++jj){
        float mn = fmaxf(mrun[jj], pmax[jj]);
        scl[jj] = __expf(mrun[jj] - mn);
        mrun[jj] = mn;
        lrun[jj] *= scl[jj];
      }
      #pragma unroll
      for (int n = 0; n < 8; ++n)
        #pragma unroll
        for (int jj = 0; jj < 4; ++jj) acc_o[n][jj] *= scl[jj];
    }
    float psum[4] = {0.f, 0.f, 0.f, 0.f};
    #pragma unroll
    for (int j = 0; j < 4; ++j)
      #pragma unroll
      for (int jj = 0; jj < 4; ++jj){
        float p = __expf(sacc[j][jj] - mrun[jj]);
        sacc[j][jj] = p;
        psum[jj] += p;
      }
    #pragma unroll
    for (int jj = 0; jj < 4; ++jj){
      float ps = psum[jj];
      #pragma unroll
      for (int mk = 1; mk < 16; mk <<= 1) ps += __shfl_xor(ps, mk, 64);
      lrun[jj] += ps;
    }
    unsigned short* Pw = Psm[wave];
    #pragma unroll
    for (int j = 0; j < 4; ++j)
      #pragma unroll
      for (int jj = 0; jj < 4; ++jj){
        int prow = lg * 4 + jj, pcol = j * 16 + lr;
        int bo = prow * 128 + pcol * 2;
        bo ^= (prow & 7) << 4;
        *(unsigned short*)((char*)Pw + bo) = f2bf(sacc[j][jj]);
      }
    __syncthreads();
    #pragma unroll
    for (int k2 = 0; k2 < 2; ++k2){
      int bo = lr * 128 + (k2 * 32 + lg * 8) * 2;
      bo ^= (lr & 7) << 4;
      bf16x8 pf = *(const bf16x8*)((const char*)Pw + bo);
      #pragma unroll
      for (int n = 0; n < 8; ++n){
        int dd = n * 16 + lr;
        int vb_ = dd * 128 + (k2 * 32 + lg * 8) * 2;
        vb_ ^= (dd & 7) << 4;
        bf16x8 vf = *(const bf16x8*)((const char*)Vsm + vb_);
        acc_o[n] = __builtin_amdgcn_mfma_f32_16x16x32_bf16(pf, vf, acc_o[n], 0, 0, 0);
      }
    }
  }
  #pragma unroll
  for (int jj = 0; jj < 4; ++jj) lrun[jj] = 1.f / lrun[jj];
  #pragma unroll
  for (int n = 0; n < 8; ++n)
    #pragma unroll
    for (int jj = 0; jj < 4; ++jj){
      int row = q0 + lg * 4 + jj;
      int col = hh * HDIM + n * 16 + lr;
      a2[(size_t)row * NCOL2 + col] = f2bf(acc_o[n][jj] * lrun[jj]);
    }
}

// ------------------------------------------------------------------ launch
extern "C" void kernel_launch(void* const* d_in, const int* in_sizes, int n_in,
                              void* d_out, int out_size, void* d_ws, size_t ws_size,
                              hipStream_t stream){
  const float* x       = (const float*)d_in[0];
  const float* vec     = (const float*)d_in[1];
  const float* pe      = (const float*)d_in[2];
  const float* mod_w   = (const float*)d_in[3];
  const float* mod_b   = (const float*)d_in[4];
  const float* lin1_w  = (const float*)d_in[5];
  const float* lin1_b  = (const float*)d_in[6];
  const float* lin2_w  = (const float*)d_in[7];
  const float* lin2_b  = (const float*)d_in[8];
  const float* q_scale = (const float*)d_in[9];
  const float* k_scale = (const float*)d_in[10];
  float* out = (float*)d_out;

  char* ws = (char*)d_ws;
  size_t off = 0;
  auto alloc = [&](size_t bytes){ void* p = ws + off; off += (bytes + 255) & ~(size_t)255; return p; };
  float* sv            = (float*)alloc((size_t)HID * 4);
  float* mod           = (float*)alloc((size_t)MOD3 * 4);
  unsigned short* xmod = (unsigned short*)alloc((size_t)SEQ * HID * 2);
  unsigned short* wt2  = (unsigned short*)alloc((size_t)HID * NCOL2 * 2);
  unsigned short* a2   = (unsigned short*)alloc((size_t)SEQ * NCOL2 * 2);
  // dead-after-attn region (contiguous): lin2 bf16 partials alias it (KSPLIT*12.6MB = 101MB)
  unsigned short* qb   = (unsigned short*)alloc((size_t)NHEADS * SEQ * HDIM * 2);
  unsigned short* kb   = (unsigned short*)alloc((size_t)NHEADS * SEQ * HDIM * 2);
  unsigned short* vb   = (unsigned short*)alloc((size_t)NHEADS * SEQ * HDIM * 2);
  unsigned short* vt   = (unsigned short*)alloc((size_t)NHEADS * SEQ * HDIM * 2);
  unsigned short* wt1  = (unsigned short*)alloc((size_t)NCOL1 * HID * 2);
  unsigned short* hq   = (unsigned short*)alloc((size_t)SEQ * QKVW * 2);
  unsigned short* part = qb;

  silu_kernel<<<12, 256, 0, stream>>>(vec, sv);
  mod_gemv<<<MOD3 / 32, 256, 0, stream>>>(sv, mod_w, mod_b, mod);
  transpose_f2b<<<dim3(NCOL1 / 64, HID / 64), 256, 0, stream>>>(lin1_w, wt1, HID, NCOL1);
  transpose_f2b<<<dim3(HID / 64, NCOL2 / 64), 256, 0, stream>>>(lin2_w, wt2, NCOL2, HID);
  ln_mod_kernel<<<SEQ, 256, 0, stream>>>(x, mod, xmod);
  // lin1: 256x256 tiles, grid 84x8; fused GELU for mlp cols, compact hq for qkv cols
  gemm256<0><<<dim3(NCOL1 / 256, SEQ / 256, 1), 512, 0, stream>>>(
      xmod, wt1, lin1_b, hq, a2, SEQ, NCOL1, HID, HID, HID);
  qkv_prep<<<dim3(SEQ, NHEADS), 64, 0, stream>>>(hq, pe, q_scale, k_scale, qb, kb, vb);
  transpose_b2b_head<<<dim3(HDIM / 64, SEQ / 64, NHEADS), 256, 0, stream>>>(vb, vt, SEQ, HDIM);
  attn_kernel<<<dim3(SEQ / 64, NHEADS), 256, 0, stream>>>(qb, kb, vt, a2);
  // lin2: 256x256 tiles, split-K 8, grid 12x8x8 = 768 = 3 exact rounds; bf16 partials
  gemm256<2><<<dim3(HID / 256, SEQ / 256, KSPLIT), 512, 0, stream>>>(
      a2, wt2, nullptr, part, nullptr, SEQ, HID, NCOL2, NCOL2, NCOL2 / KSPLIT);
  reduce_lin2<<<SEQ * HID / 4 / 256, 256, 0, stream>>>(part, x, mod + 2 * HID, lin2_b, out);
}

// Round 19
// 798.790 us; speedup vs baseline: 1.0349x; 1.0349x over previous
//
#include <hip/hip_runtime.h>
#include <hip/hip_bf16.h>
#include <stdint.h>

#define SEQ   2048
#define HID   3072
#define NHEADS 24
#define HDIM  128
#define MLPD  12288
#define NCOL1 21504   // 3*HID + MLPD
#define NCOL2 15360   // HID + MLPD
#define MOD3  9216    // 3*HID
#define QKVW  9216    // compact qkv width
#define KSPLIT 8      // lin2 split-K factor

typedef __attribute__((ext_vector_type(4))) float f32x4;
typedef __attribute__((ext_vector_type(8))) short bf16x8;
typedef __attribute__((ext_vector_type(4))) unsigned short u16x4;
typedef __attribute__((ext_vector_type(2))) unsigned short u16x2;

#define VMC(n) asm volatile("s_waitcnt vmcnt(" #n ")" ::: "memory")
#define SB()   __builtin_amdgcn_sched_barrier(0)

__device__ __forceinline__ unsigned short f2bf(float f){
  unsigned u = __float_as_uint(f);
  u = (u + 0x7fffu + ((u >> 16) & 1u)) >> 16;   // RTNE
  return (unsigned short)u;
}
__device__ __forceinline__ float bf2f(unsigned short u){
  return __uint_as_float(((unsigned)u) << 16);
}

__device__ __forceinline__ void gload_lds16(const void* g, void* l){
  __builtin_amdgcn_global_load_lds(
      (const __attribute__((address_space(1))) unsigned int*)g,
      (__attribute__((address_space(3))) unsigned int*)l, 16, 0, 0);
}

__device__ __forceinline__ float gelu_tanh(float x){
  float u = 0.7978845608028654f * (x + 0.044715f * x * x * x);
  float t = 1.f - 2.f / (__expf(2.f * u) + 1.f);   // tanh(u)
  return 0.5f * x * (1.f + t);
}

// ---------------------------------------------------------------- small ops
__global__ void silu_kernel(const float* __restrict__ vec, float* __restrict__ sv){
  int i = blockIdx.x * 256 + threadIdx.x;
  if (i < HID){ float v = vec[i]; sv[i] = v / (1.f + __expf(-v)); }
}

__global__ void mod_gemv(const float* __restrict__ sv, const float* __restrict__ W,
                         const float* __restrict__ b, float* __restrict__ mod){
  int n  = blockIdx.x * 32 + (threadIdx.x & 31);
  int ks = threadIdx.x >> 5;               // 0..7, each 384 k
  float acc = 0.f;
  int k0 = ks * 384;
  #pragma unroll 4
  for (int k = k0; k < k0 + 384; ++k)
    acc += sv[k] * W[(size_t)k * MOD3 + n];
  __shared__ float red[8][32];
  red[ks][threadIdx.x & 31] = acc;
  __syncthreads();
  if (ks == 0){
    float a = 0.f;
    #pragma unroll
    for (int i = 0; i < 8; ++i) a += red[i][threadIdx.x & 31];
    mod[n] = a + b[n];
  }
}

__global__ __launch_bounds__(256)
void ln_mod_kernel(const float* __restrict__ x, const float* __restrict__ mod,
                   unsigned short* __restrict__ xmod){
  int l = blockIdx.x, t = threadIdx.x;
  const float* row = x + (size_t)l * HID;
  f32x4 v[3];
  float s = 0.f, s2 = 0.f;
  #pragma unroll
  for (int i = 0; i < 3; ++i){
    v[i] = *(const f32x4*)(row + (t + i * 256) * 4);
    #pragma unroll
    for (int j = 0; j < 4; ++j){ s += v[i][j]; s2 += v[i][j] * v[i][j]; }
  }
  #pragma unroll
  for (int m = 1; m < 64; m <<= 1){ s += __shfl_xor(s, m, 64); s2 += __shfl_xor(s2, m, 64); }
  __shared__ float red[8];
  int wv = t >> 6, ln = t & 63;
  if (ln == 0){ red[wv] = s; red[4 + wv] = s2; }
  __syncthreads();
  s  = red[0] + red[1] + red[2] + red[3];
  s2 = red[4] + red[5] + red[6] + red[7];
  float mu  = s * (1.f / HID);
  float var = s2 * (1.f / HID) - mu * mu;
  float rs  = rsqrtf(var + 1e-6f);
  #pragma unroll
  for (int i = 0; i < 3; ++i){
    int c = (t + i * 256) * 4;
    f32x4 sh = *(const f32x4*)(mod + c);
    f32x4 sc = *(const f32x4*)(mod + HID + c);
    u16x4 o;
    #pragma unroll
    for (int j = 0; j < 4; ++j){
      float xn = (v[i][j] - mu) * rs;
      o[j] = f2bf((1.f + sc[j]) * xn + sh[j]);
    }
    *(u16x4*)(xmod + (size_t)l * HID + c) = o;
  }
}

// fp32 (R x C) -> bf16 (C x R)
__global__ __launch_bounds__(256)
void transpose_f2b(const float* __restrict__ in, unsigned short* __restrict__ out,
                   int R, int C){
  __shared__ float tile[64][65];
  int rt = blockIdx.y * 64, ct = blockIdx.x * 64;
  int t = threadIdx.x;
  int r0 = t >> 4, c0 = (t & 15) * 4;
  #pragma unroll
  for (int ph = 0; ph < 4; ++ph){
    int r = r0 + ph * 16;
    f32x4 v = *(const f32x4*)(in + (size_t)(rt + r) * C + ct + c0);
    tile[r][c0 + 0] = v[0]; tile[r][c0 + 1] = v[1];
    tile[r][c0 + 2] = v[2]; tile[r][c0 + 3] = v[3];
  }
  __syncthreads();
  #pragma unroll
  for (int ph = 0; ph < 4; ++ph){
    int r = r0 + ph * 16;
    u16x4 o;
    #pragma unroll
    for (int i = 0; i < 4; ++i) o[i] = f2bf(tile[c0 + i][r]);
    *(u16x4*)(out + (size_t)(ct + r) * R + rt + c0) = o;
  }
}

// per-head bf16 (R x C) -> bf16 (C x R)   (V -> V^T)
__global__ __launch_bounds__(256)
void transpose_b2b_head(const unsigned short* __restrict__ in,
                        unsigned short* __restrict__ out, int R, int C){
  __shared__ unsigned short tile[64][68];
  int h = blockIdx.z;
  const unsigned short* inh = in + (size_t)h * R * C;
  unsigned short* outh = out + (size_t)h * R * C;
  int rt = blockIdx.y * 64, ct = blockIdx.x * 64;
  int t = threadIdx.x;
  int r0 = t >> 4, c0 = (t & 15) * 4;
  #pragma unroll
  for (int ph = 0; ph < 4; ++ph){
    int r = r0 + ph * 16;
    u16x4 v = *(const u16x4*)(inh + (size_t)(rt + r) * C + ct + c0);
    tile[r][c0 + 0] = v[0]; tile[r][c0 + 1] = v[1];
    tile[r][c0 + 2] = v[2]; tile[r][c0 + 3] = v[3];
  }
  __syncthreads();
  #pragma unroll
  for (int ph = 0; ph < 4; ++ph){
    int r = r0 + ph * 16;
    u16x4 o;
    #pragma unroll
    for (int i = 0; i < 4; ++i) o[i] = tile[c0 + i][r];
    *(u16x4*)(outh + (size_t)(ct + r) * R + rt + c0) = o;
  }
}

// RMS-norm + RoPE for q,k; passthrough v. One wave per (l, head). hq is bf16 [SEQ][9216].
__global__ void qkv_prep(const unsigned short* __restrict__ hq, const float* __restrict__ pe,
                         const float* __restrict__ qscale, const float* __restrict__ kscale,
                         unsigned short* __restrict__ qb, unsigned short* __restrict__ kb,
                         unsigned short* __restrict__ vb){
  int l = blockIdx.x, hh = blockIdx.y, lane = threadIdx.x;  // 64 threads
  const unsigned short* row = hq + (size_t)l * QKVW;
  int d = lane * 2;
  u16x2 qv = *(const u16x2*)(row + hh * HDIM + d);
  u16x2 kv = *(const u16x2*)(row + HID + hh * HDIM + d);
  u16x2 vv = *(const u16x2*)(row + 2 * HID + hh * HDIM + d);
  float qx = bf2f(qv[0]), qy = bf2f(qv[1]);
  float kx = bf2f(kv[0]), ky = bf2f(kv[1]);
  float sq = qx * qx + qy * qy;
  float sk = kx * kx + ky * ky;
  #pragma unroll
  for (int m = 1; m < 64; m <<= 1){ sq += __shfl_xor(sq, m, 64); sk += __shfl_xor(sk, m, 64); }
  float rq = rsqrtf(sq * (1.f / HDIM) + 1e-6f);
  float rk = rsqrtf(sk * (1.f / HDIM) + 1e-6f);
  float2 qs2 = *(const float2*)(qscale + d);
  float2 ks2 = *(const float2*)(kscale + d);
  float q0 = qx * rq * qs2.x, q1 = qy * rq * qs2.y;
  float k0 = kx * rk * ks2.x, k1 = ky * rk * ks2.y;
  f32x4 p4 = *(const f32x4*)(pe + (size_t)l * 256 + lane * 4);  // [p][a][b]
  const float sscl = 0.08838834764831845f;  // 1/sqrt(128), folded into q
  float qo0 = (p4[0] * q0 + p4[1] * q1) * sscl;
  float qo1 = (p4[2] * q0 + p4[3] * q1) * sscl;
  float ko0 =  p4[0] * k0 + p4[1] * k1;
  float ko1 =  p4[2] * k0 + p4[3] * k1;
  size_t base = ((size_t)hh * SEQ + l) * HDIM + d;
  u16x2 o;
  o[0] = f2bf(qo0); o[1] = f2bf(qo1); *(u16x2*)(qb + base) = o;
  o[0] = f2bf(ko0); o[1] = f2bf(ko1); *(u16x2*)(kb + base) = o;
  o[0] = vv[0];     o[1] = vv[1];     *(u16x2*)(vb + base) = o;
}

// --------------------- 256x256 row-split half-tile GEMM (2 barriers/K-tile, R17 frozen) ---------------------
//   P0  : gate {Au,Bu}(t) VMC(8|4); barrier; read Au(8)+Bu(4); stage Bl(t+1); 16 MFMA
//   P12 : gate {Bl,Al}(t) VMC(6|0); barrier; read Bl(4)+Al(8); stage Al(t+1),Au(t+2); 32 MFMA
//   P3  : (no barrier/gate/reads) stage Bu(t+2); 16 MFMA
template<int EPI>
__global__ __launch_bounds__(512)
void gemm256(const unsigned short* __restrict__ A, const unsigned short* __restrict__ BT,
             const float* __restrict__ bias, unsigned short* __restrict__ out0,
             unsigned short* __restrict__ out1,
             int M, int N, int ldA, int ldB, int kchunk){
  __shared__ unsigned short Ls[65536];   // A: [buf][half][128*64] @0; B same @32768. 128 KB.
  int nxy = gridDim.x * gridDim.y;
  int nwg = nxy * gridDim.z;
  int fid = (blockIdx.z * gridDim.y + blockIdx.y) * gridDim.x + blockIdx.x;
  int nid = (fid & 7) * (nwg >> 3) + (fid >> 3);    // nwg % 8 == 0 by grid choice
  int ksz = nid / nxy, rem = nid % nxy;
  int bm  = rem % gridDim.y, bn = rem / gridDim.y;  // bm-fast within XCD chunk
  int k0 = ksz * kchunk;
  int nk = kchunk >> 6;                  // BK = 64
  int tid = threadIdx.x, wave = tid >> 6, lane = tid & 63, lg = lane >> 4, lr = lane & 15;
  int wr = wave >> 2, wc = wave & 3;     // 2 x 4 wave grid

  // staging: half = 128 rows x 64 cols; granule g in [0,1024): row=g>>3, cg=g&7 (16B)
  int rh = tid >> 3;                     // rows 0..63 (g0); g1 adds 64 (row&7 unchanged)
  int sc = (((tid & 7) ^ (rh & 7)) * 8); // swizzled source col (elements)
  const unsigned short* pA0 = A  + (size_t)(bm * 256 + rh     ) * ldA + k0 + sc;
  const unsigned short* pA1 = A  + (size_t)(bm * 256 + rh + 64) * ldA + k0 + sc;
  const unsigned short* pB0 = BT + (size_t)(bn * 256 + rh     ) * ldB + k0 + sc;
  const unsigned short* pB1 = BT + (size_t)(bn * 256 + rh + 64) * ldB + k0 + sc;
  int d0 = (wave * 64) * 8, d1 = (512 + wave * 64) * 8;

  auto stageA = [&](int t, int half){
    unsigned short* h = Ls + (((t & 1) * 2 + half) << 13);
    size_t ro = (size_t)(half * 128) * ldA + t * 64;
    gload_lds16(pA0 + ro, h + d0);
    gload_lds16(pA1 + ro, h + d1);
  };
  auto stageB = [&](int t, int half){
    unsigned short* h = Ls + 32768 + (((t & 1) * 2 + half) << 13);
    size_t ro = (size_t)(half * 128) * ldB + t * 64;
    gload_lds16(pB0 + ro, h + d0);
    gload_lds16(pB1 + ro, h + d1);
  };

  // ds_read offsets (elements) within a half, swizzle-matched
  int offA[4][2], offB[2][2];
  #pragma unroll
  for (int mm = 0; mm < 4; ++mm){
    int row = wr * 64 + mm * 16 + lr;
    #pragma unroll
    for (int ks = 0; ks < 2; ++ks)
      offA[mm][ks] = row * 64 + (((ks * 4 + lg) ^ (row & 7)) * 8);
  }
  #pragma unroll
  for (int nn = 0; nn < 2; ++nn){
    int row = wc * 32 + nn * 16 + lr;
    #pragma unroll
    for (int ks = 0; ks < 2; ++ks)
      offB[nn][ks] = row * 64 + (((ks * 4 + lg) ^ (row & 7)) * 8);
  }

  const f32x4 fz = 0.0f;
  f32x4 acc[8][4];   // [m: 0-3 upper rows, 4-7 lower][n: 0-1 upper cols, 2-3 lower]
  #pragma unroll
  for (int i = 0; i < 8; ++i)
    #pragma unroll
    for (int j = 0; j < 4; ++j) acc[i][j] = fz;

  // prologue: Au0 Bu0 Bl0 Al0 Au1 Bu1
  stageA(0, 0); stageB(0, 0); stageB(0, 1); stageA(0, 1);
  if (nk > 1){ stageA(1, 0); stageB(1, 0); }

  for (int t = 0; t < nk; ++t){
    const unsigned short* Au_ = Ls + (((t & 1) * 2 + 0) << 13);
    const unsigned short* Al_ = Ls + (((t & 1) * 2 + 1) << 13);
    const unsigned short* Bu_ = Ls + 32768 + (((t & 1) * 2 + 0) << 13);
    const unsigned short* Bl_ = Ls + 32768 + (((t & 1) * 2 + 1) << 13);
    bool more1 = (t + 1 < nk), more2 = (t + 2 < nk);
    bf16x8 am[4][2], am4[4][2], b01[2][2], b23[2][2];
    // ---------------- P0: gate {Au,Bu}(t); read Au/Bu frags; stage Bl(t+1); 16 MFMA
    if (more1) VMC(8); else VMC(4);
    __builtin_amdgcn_s_barrier();
    SB();
    #pragma unroll
    for (int mm = 0; mm < 4; ++mm)
      #pragma unroll
      for (int ks = 0; ks < 2; ++ks) am[mm][ks] = *(const bf16x8*)&Au_[offA[mm][ks]];
    #pragma unroll
    for (int nn = 0; nn < 2; ++nn)
      #pragma unroll
      for (int ks = 0; ks < 2; ++ks) b01[nn][ks] = *(const bf16x8*)&Bu_[offB[nn][ks]];
    if (more1) stageB(t + 1, 1);
    SB();
    __builtin_amdgcn_s_setprio(1);
    #pragma unroll
    for (int mm = 0; mm < 4; ++mm)
      #pragma unroll
      for (int nn = 0; nn < 2; ++nn)
        #pragma unroll
        for (int ks = 0; ks < 2; ++ks)
          acc[mm][nn] = __builtin_amdgcn_mfma_f32_16x16x32_bf16(am[mm][ks], b01[nn][ks], acc[mm][nn], 0, 0, 0);
    __builtin_amdgcn_s_setprio(0);
    SB();
    // ---------------- P12: gate {Bl,Al}(t); read Bl/Al frags; stage Al(t+1),Au(t+2); 32 MFMA
    if (more1) VMC(6); else VMC(0);
    __builtin_amdgcn_s_barrier();
    SB();
    #pragma unroll
    for (int nn = 0; nn < 2; ++nn)
      #pragma unroll
      for (int ks = 0; ks < 2; ++ks) b23[nn][ks] = *(const bf16x8*)&Bl_[offB[nn][ks]];
    #pragma unroll
    for (int mm = 0; mm < 4; ++mm)
      #pragma unroll
      for (int ks = 0; ks < 2; ++ks) am4[mm][ks] = *(const bf16x8*)&Al_[offA[mm][ks]];
    if (more1) stageA(t + 1, 1);
    if (more2) stageA(t + 2, 0);
    SB();
    __builtin_amdgcn_s_setprio(1);
    #pragma unroll
    for (int mm = 0; mm < 4; ++mm)
      #pragma unroll
      for (int nn = 0; nn < 2; ++nn)
        #pragma unroll
        for (int ks = 0; ks < 2; ++ks)
          acc[mm][nn + 2] = __builtin_amdgcn_mfma_f32_16x16x32_bf16(am[mm][ks], b23[nn][ks], acc[mm][nn + 2], 0, 0, 0);
    #pragma unroll
    for (int mm = 0; mm < 4; ++mm)
      #pragma unroll
      for (int nn = 0; nn < 2; ++nn)
        #pragma unroll
        for (int ks = 0; ks < 2; ++ks)
          acc[mm + 4][nn] = __builtin_amdgcn_mfma_f32_16x16x32_bf16(am4[mm][ks], b01[nn][ks], acc[mm + 4][nn], 0, 0, 0);
    __builtin_amdgcn_s_setprio(0);
    SB();
    // ---------------- P3 (no barrier/gate/reads): stage Bu(t+2); 16 MFMA
    if (more2) stageB(t + 2, 0);
    SB();
    __builtin_amdgcn_s_setprio(1);
    #pragma unroll
    for (int mm = 0; mm < 4; ++mm)
      #pragma unroll
      for (int nn = 0; nn < 2; ++nn)
        #pragma unroll
        for (int ks = 0; ks < 2; ++ks)
          acc[mm + 4][nn + 2] = __builtin_amdgcn_mfma_f32_16x16x32_bf16(am4[mm][ks], b23[nn][ks], acc[mm + 4][nn + 2], 0, 0, 0);
    __builtin_amdgcn_s_setprio(0);
    SB();
  }

  // output mapping: row = bm*256 + wr*64 + (m&3)*16 + (m>>2)*128 + lg*4 + jj
  //                 col = bn*256 + wc*32 + (n&1)*16 + (n>>1)*128 + lr
  if constexpr (EPI == 0){
    if (bn < MOD3 / 256){                       // block-uniform: whole tile -> hq
      #pragma unroll
      for (int m = 0; m < 8; ++m)
        #pragma unroll
        for (int n = 0; n < 4; ++n){
          int col = bn * 256 + wc * 32 + (n & 1) * 16 + (n >> 1) * 128 + lr;
          float bv = bias[col];
          #pragma unroll
          for (int jj = 0; jj < 4; ++jj){
            int row = bm * 256 + wr * 64 + (m & 3) * 16 + (m >> 2) * 128 + lg * 4 + jj;
            out0[(size_t)row * QKVW + col] = f2bf(acc[m][n][jj] + bv);
          }
        }
    } else {                                    // whole tile -> gelu -> a2
      #pragma unroll
      for (int m = 0; m < 8; ++m)
        #pragma unroll
        for (int n = 0; n < 4; ++n){
          int col = bn * 256 + wc * 32 + (n & 1) * 16 + (n >> 1) * 128 + lr;
          float bv = bias[col];
          #pragma unroll
          for (int jj = 0; jj < 4; ++jj){
            int row = bm * 256 + wr * 64 + (m & 3) * 16 + (m >> 2) * 128 + lg * 4 + jj;
            out1[(size_t)row * NCOL2 + (col - 2 * HID)] = f2bf(gelu_tanh(acc[m][n][jj] + bv));
          }
        }
    }
  } else {
    unsigned short* P = out0 + (size_t)ksz * M * N;
    #pragma unroll
    for (int m = 0; m < 8; ++m)
      #pragma unroll
      for (int n = 0; n < 4; ++n){
        int col = bn * 256 + wc * 32 + (n & 1) * 16 + (n >> 1) * 128 + lr;
        #pragma unroll
        for (int jj = 0; jj < 4; ++jj){
          int row = bm * 256 + wr * 64 + (m & 3) * 16 + (m >> 2) * 128 + lg * 4 + jj;
          P[(size_t)row * N + col] = f2bf(acc[m][n][jj]);
        }
      }
  }
}

// split-K reduce (bf16 partials) + bias + gate*(.) + residual  (lin2 epilogue)
__global__ __launch_bounds__(256)
void reduce_lin2(const unsigned short* __restrict__ part, const float* __restrict__ x,
                 const float* __restrict__ gate, const float* __restrict__ bias,
                 float* __restrict__ out){
  int i4 = blockIdx.x * 256 + threadIdx.x;          // over 2048*3072/4
  int c4 = i4 % (HID / 4);
  f32x4 s = 0.0f;
  #pragma unroll
  for (int ks = 0; ks < KSPLIT; ++ks){
    u16x4 p = *(const u16x4*)(part + (size_t)ks * SEQ * HID + (size_t)i4 * 4);
    #pragma unroll
    for (int j = 0; j < 4; ++j) s[j] += bf2f(p[j]);
  }
  f32x4 xv = *(const f32x4*)(x + (size_t)i4 * 4);
  f32x4 gv = *(const f32x4*)(gate + c4 * 4);
  f32x4 bv = *(const f32x4*)(bias + c4 * 4);
  f32x4 o;
  #pragma unroll
  for (int j = 0; j < 4; ++j) o[j] = xv[j] + gv[j] * (s[j] + bv[j]);
  *(f32x4*)(out + (size_t)i4 * 4) = o;
}

// -------------------------------------------------------- flash attention
__global__ __launch_bounds__(256)
void attn_kernel(const unsigned short* __restrict__ qb, const unsigned short* __restrict__ kb,
                 const unsigned short* __restrict__ vt, unsigned short* __restrict__ a2){
  __shared__ unsigned short Ksm[64 * 128];   // [kv][d], XOR-swizzled
  __shared__ unsigned short Vsm[128 * 64];   // [d][kv], XOR-swizzled
  __shared__ unsigned short Psm[4][16 * 64]; // per-wave [q][kv], XOR-swizzled
  int fid = blockIdx.y * gridDim.x + blockIdx.x;   // 768 blocks
  int nid = (fid & 7) * 96 + (fid >> 3);
  int hh = nid / (SEQ / 64), qt = nid % (SEQ / 64);
  int tid = threadIdx.x, wave = tid >> 6, lane = tid & 63, lg = lane >> 4, lr = lane & 15;
  const unsigned short* Kh = kb + (size_t)hh * SEQ * HDIM;
  const unsigned short* Vh = vt + (size_t)hh * HDIM * SEQ;
  const unsigned short* Qh = qb + (size_t)hh * SEQ * HDIM;
  int q0 = qt * 64 + wave * 16;

  bf16x8 aq[4];
  #pragma unroll
  for (int kk = 0; kk < 4; ++kk)
    aq[kk] = *(const bf16x8*)(Qh + (size_t)(q0 + lr) * HDIM + kk * 32 + lg * 8);

  const f32x4 fzero = 0.0f;
  f32x4 acc_o[8];
  #pragma unroll
  for (int n = 0; n < 8; ++n) acc_o[n] = fzero;
  float mrun[4] = {-1e30f, -1e30f, -1e30f, -1e30f};
  float lrun[4] = {0.f, 0.f, 0.f, 0.f};

  for (int t = 0; t < SEQ / 64; ++t){
    __syncthreads();
    const unsigned short* Kt = Kh + (size_t)t * 64 * HDIM;
    const unsigned short* Vt = Vh + t * 64;
    #pragma unroll
    for (int r = 0; r < 4; ++r){
      int G  = r * 256 + tid;
      int Gs = G ^ ((G >> 4) & 7);
      gload_lds16(Kt + Gs * 8, (void*)&Ksm[(r * 256 + wave * 64) * 8]);
      int Gv = G ^ ((G >> 3) & 7);
      gload_lds16(Vt + (size_t)(Gv >> 3) * SEQ + (Gv & 7) * 8,
                  (void*)&Vsm[(r * 256 + wave * 64) * 8]);
    }
    __syncthreads();

    f32x4 sacc[4];
    #pragma unroll
    for (int j = 0; j < 4; ++j) sacc[j] = fzero;
    #pragma unroll
    for (int j = 0; j < 4; ++j){
      int kv = j * 16 + lr;
      #pragma unroll
      for (int kk = 0; kk < 4; ++kk){
        int bo = kv * 256 + (kk * 32 + lg * 8) * 2;
        bo ^= (kv & 7) << 4;
        bf16x8 bk = *(const bf16x8*)((const char*)Ksm + bo);
        sacc[j] = __builtin_amdgcn_mfma_f32_16x16x32_bf16(aq[kk], bk, sacc[j], 0, 0, 0);
      }
    }
    float scl[4], psum[4];
    #pragma unroll
    for (int jj = 0; jj < 4; ++jj){
      float m_ = fmaxf(fmaxf(sacc[0][jj], sacc[1][jj]), fmaxf(sacc[2][jj], sacc[3][jj]));
      #pragma unroll
      for (int mk = 1; mk < 16; mk <<= 1) m_ = fmaxf(m_, __shfl_xor(m_, mk, 64));
      float mn = fmaxf(mrun[jj], m_);
      scl[jj] = __expf(mrun[jj] - mn);
      mrun[jj] = mn;
      psum[jj] = 0.f;
    }
    #pragma unroll
    for (int j = 0; j < 4; ++j)
      #pragma unroll
      for (int jj = 0; jj < 4; ++jj){
        float p = __expf(sacc[j][jj] - mrun[jj]);
        sacc[j][jj] = p;
        psum[jj] += p;
      }
    #pragma unroll
    for (int jj = 0; jj < 4; ++jj){
      float ps = psum[jj];
      #pragma unroll
      for (int mk = 1; mk < 16; mk <<= 1) ps += __shfl_xor(ps, mk, 64);
      lrun[jj] = lrun[jj] * scl[jj] + ps;
    }
    #pragma unroll
    for (int n = 0; n < 8; ++n)
      #pragma unroll
      for (int jj = 0; jj < 4; ++jj) acc_o[n][jj] *= scl[jj];
    unsigned short* Pw = Psm[wave];
    #pragma unroll
    for (int j = 0; j < 4; ++j)
      #pragma unroll
      for (int jj = 0; jj < 4; ++jj){
        int prow = lg * 4 + jj, pcol = j * 16 + lr;
        int bo = prow * 128 + pcol * 2;
        bo ^= (prow & 7) << 4;
        *(unsigned short*)((char*)Pw + bo) = f2bf(sacc[j][jj]);
      }
    __syncthreads();
    #pragma unroll
    for (int k2 = 0; k2 < 2; ++k2){
      int bo = lr * 128 + (k2 * 32 + lg * 8) * 2;
      bo ^= (lr & 7) << 4;
      bf16x8 pf = *(const bf16x8*)((const char*)Pw + bo);
      #pragma unroll
      for (int n = 0; n < 8; ++n){
        int dd = n * 16 + lr;
        int vb_ = dd * 128 + (k2 * 32 + lg * 8) * 2;
        vb_ ^= (dd & 7) << 4;
        bf16x8 vf = *(const bf16x8*)((const char*)Vsm + vb_);
        acc_o[n] = __builtin_amdgcn_mfma_f32_16x16x32_bf16(pf, vf, acc_o[n], 0, 0, 0);
      }
    }
  }
  #pragma unroll
  for (int jj = 0; jj < 4; ++jj) lrun[jj] = 1.f / lrun[jj];
  #pragma unroll
  for (int n = 0; n < 8; ++n)
    #pragma unroll
    for (int jj = 0; jj < 4; ++jj){
      int row = q0 + lg * 4 + jj;
      int col = hh * HDIM + n * 16 + lr;
      a2[(size_t)row * NCOL2 + col] = f2bf(acc_o[n][jj] * lrun[jj]);
    }
}

// ------------------------------------------------------------------ launch
extern "C" void kernel_launch(void* const* d_in, const int* in_sizes, int n_in,
                              void* d_out, int out_size, void* d_ws, size_t ws_size,
                              hipStream_t stream){
  const float* x       = (const float*)d_in[0];
  const float* vec     = (const float*)d_in[1];
  const float* pe      = (const float*)d_in[2];
  const float* mod_w   = (const float*)d_in[3];
  const float* mod_b   = (const float*)d_in[4];
  const float* lin1_w  = (const float*)d_in[5];
  const float* lin1_b  = (const float*)d_in[6];
  const float* lin2_w  = (const float*)d_in[7];
  const float* lin2_b  = (const float*)d_in[8];
  const float* q_scale = (const float*)d_in[9];
  const float* k_scale = (const float*)d_in[10];
  float* out = (float*)d_out;

  char* ws = (char*)d_ws;
  size_t off = 0;
  auto alloc = [&](size_t bytes){ void* p = ws + off; off += (bytes + 255) & ~(size_t)255; return p; };
  float* sv            = (float*)alloc((size_t)HID * 4);
  float* mod           = (float*)alloc((size_t)MOD3 * 4);
  unsigned short* xmod = (unsigned short*)alloc((size_t)SEQ * HID * 2);
  unsigned short* wt2  = (unsigned short*)alloc((size_t)HID * NCOL2 * 2);
  unsigned short* a2   = (unsigned short*)alloc((size_t)SEQ * NCOL2 * 2);
  // dead-after-attn region (contiguous): lin2 bf16 partials alias it (KSPLIT*12.6MB = 101MB)
  unsigned short* qb   = (unsigned short*)alloc((size_t)NHEADS * SEQ * HDIM * 2);
  unsigned short* kb   = (unsigned short*)alloc((size_t)NHEADS * SEQ * HDIM * 2);
  unsigned short* vb   = (unsigned short*)alloc((size_t)NHEADS * SEQ * HDIM * 2);
  unsigned short* vt   = (unsigned short*)alloc((size_t)NHEADS * SEQ * HDIM * 2);
  unsigned short* wt1  = (unsigned short*)alloc((size_t)NCOL1 * HID * 2);
  unsigned short* hq   = (unsigned short*)alloc((size_t)SEQ * QKVW * 2);
  unsigned short* part = qb;

  silu_kernel<<<12, 256, 0, stream>>>(vec, sv);
  mod_gemv<<<MOD3 / 32, 256, 0, stream>>>(sv, mod_w, mod_b, mod);
  transpose_f2b<<<dim3(NCOL1 / 64, HID / 64), 256, 0, stream>>>(lin1_w, wt1, HID, NCOL1);
  transpose_f2b<<<dim3(HID / 64, NCOL2 / 64), 256, 0, stream>>>(lin2_w, wt2, NCOL2, HID);
  ln_mod_kernel<<<SEQ, 256, 0, stream>>>(x, mod, xmod);
  // lin1: 256x256 tiles, grid 84x8; fused GELU for mlp cols, compact hq for qkv cols
  gemm256<0><<<dim3(NCOL1 / 256, SEQ / 256, 1), 512, 0, stream>>>(
      xmod, wt1, lin1_b, hq, a2, SEQ, NCOL1, HID, HID, HID);
  qkv_prep<<<dim3(SEQ, NHEADS), 64, 0, stream>>>(hq, pe, q_scale, k_scale, qb, kb, vb);
  transpose_b2b_head<<<dim3(HDIM / 64, SEQ / 64, NHEADS), 256, 0, stream>>>(vb, vt, SEQ, HDIM);
  attn_kernel<<<dim3(SEQ / 64, NHEADS), 256, 0, stream>>>(qb, kb, vt, a2);
  // lin2: 256x256 tiles, split-K 8, grid 12x8x8 = 768 = 3 exact rounds; bf16 partials
  gemm256<2><<<dim3(HID / 256, SEQ / 256, KSPLIT), 512, 0, stream>>>(
      a2, wt2, nullptr, part, nullptr, SEQ, HID, NCOL2, NCOL2, NCOL2 / KSPLIT);
  reduce_lin2<<<SEQ * HID / 4 / 256, 256, 0, stream>>>(part, x, mod + 2 * HID, lin2_b, out);
}